// Round 11
// baseline (500.846 us; speedup 1.0000x reference)
//
#include <hip/hip_runtime.h>
#include <math.h>

#define DH 128
#define EPSB 1e-5f
#define MAXB 832     // max buckets (N <= 106496)
#define BCAP 2560    // bucket capacity (mean ~2046 at E/N=16, +11 sigma)
#define LDAP 136     // padded LDS row stride (ushorts)

typedef __attribute__((ext_vector_type(8))) short short8;
typedef __attribute__((ext_vector_type(4))) float f32x4;

static __device__ __forceinline__ unsigned short f2bf(float f) {
    unsigned u = __float_as_uint(f);
    u += 0x7fffu + ((u >> 16) & 1u);
    return (unsigned short)(u >> 16);
}
static __device__ __forceinline__ float bf2f(unsigned short h) {
    return __uint_as_float(((unsigned)h) << 16);
}
static __device__ __forceinline__ float blo(unsigned u) { return __uint_as_float(u << 16); }
static __device__ __forceinline__ float bhi(unsigned u) { return __uint_as_float(u & 0xFFFF0000u); }

// ---------------- pass A: edge bucketing + graph bounds + W fragmentize ----------------

__launch_bounds__(256)
__global__ void k_bucketA(const int* __restrict__ src, const int* __restrict__ dst,
                          int* __restrict__ gcur, int* __restrict__ bbuf,
                          const int* __restrict__ batch, int* __restrict__ starts,
                          const float* __restrict__ W0, const float* __restrict__ W1,
                          const float* __restrict__ W2, unsigned short* __restrict__ Wf0,
                          int E, int NB, int chunk, int N, int G)
{
    const int t = threadIdx.x;

    if (blockIdx.x >= 512) {            // ---- W fragmentize ----
        int fid = (blockIdx.x - 512) * 4 + (t >> 6);   // 0..191
        int lane = t & 63;
        int l = fid >> 6, f = fid & 63;
        const float* W = (l == 0) ? W0 : (l == 1) ? W1 : W2;
        unsigned short* Wf = Wf0 + (size_t)l * 32768;
        int nt = f & 3, s = (f >> 2) & 3, p = (f >> 4) & 1, nh = f >> 5;
        int n = nh * 64 + nt * 16 + (lane & 15);
        int kbase = s * 32 + (lane >> 4) * 8;
        unsigned short o[8];
#pragma unroll
        for (int j = 0; j < 8; ++j) {
            float w = W[(size_t)(kbase + j) * DH + n];
            unsigned short h = f2bf(w);
            o[j] = p ? f2bf(w - bf2f(h)) : h;
        }
        unsigned short* d = Wf + (size_t)f * 512 + lane * 8;
        *(ushort4*)d       = make_ushort4(o[0], o[1], o[2], o[3]);
        *(ushort4*)(d + 4) = make_ushort4(o[4], o[5], o[6], o[7]);
        return;
    }

    __shared__ int cnt[MAXB];
    __shared__ int base[MAXB];

    for (int i = blockIdx.x * 256 + t; i < N; i += 512 * 256) {
        int b = batch[i];
        if (i == 0) { starts[0] = 0; starts[G] = N; }
        else if (batch[i - 1] != b) starts[b] = i;
    }

    for (int i = t; i < NB; i += 256) cnt[i] = 0;
    __syncthreads();
    const int e0 = blockIdx.x * chunk;
    const int e1 = min(E, e0 + chunk);
    for (int e = e0 + t; e < e1; e += 256)
        atomicAdd(&cnt[dst[e] >> 7], 1);
    __syncthreads();
    for (int i = t; i < NB; i += 256) {
        int c = cnt[i];
        base[i] = (c > 0) ? atomicAdd(&gcur[i], c) : 0;
        cnt[i] = 0;
    }
    __syncthreads();
    for (int e = e0 + t; e < e1; e += 256) {
        int d = dst[e];
        int b = d >> 7;
        int o = base[b] + atomicAdd(&cnt[b], 1);
        if (o < BCAP) bbuf[(size_t)b * BCAP + o] = (src[e] << 7) | (d & 127);
    }
}

// ---------------- pass B: per-bucket deg/dinv/rowinfo + in-place csr scatter ----------------

__launch_bounds__(256)
__global__ void k_bfinal(const int* __restrict__ gcur, int* __restrict__ bbuf,
                         int2* __restrict__ rowinfo, float* __restrict__ dinv, int N)
{
    __shared__ int ebuf[BCAP];
    __shared__ int dcnt[128];
    __shared__ int sp[128];
    const int b = blockIdx.x, t = threadIdx.x;
    const int c = min(gcur[b], BCAP);
    const int base = b * BCAP;
    int* p = bbuf + base;
    for (int i = t; i < c; i += 256) ebuf[i] = p[i];
    if (t < 128) dcnt[t] = 0;
    __syncthreads();
    for (int i = t; i < c; i += 256) atomicAdd(&dcnt[ebuf[i] & 127], 1);
    __syncthreads();
    if (t < 128) sp[t] = dcnt[t];
    __syncthreads();
    for (int off = 1; off < 128; off <<= 1) {
        int u = (t < 128 && t >= off) ? sp[t - off] : 0;
        __syncthreads();
        if (t < 128) sp[t] += u;
        __syncthreads();
    }
    if (t < 128) {
        sp[t] -= dcnt[t];
        int d = b * 128 + t;
        if (d < N) {
            rowinfo[d] = make_int2(base + sp[t], base + sp[t] + dcnt[t]);
            dinv[d] = rsqrtf((float)(dcnt[t] + 1));
        }
        dcnt[t] = 0;
    }
    __syncthreads();
    for (int i = t; i < c; i += 256) {
        int e = ebuf[i];
        int dl = e & 127;
        int o = atomicAdd(&dcnt[dl], 1);
        p[sp[dl] + o] = e >> 7;
    }
}

// ---------------- GEMM layer 0: split at staging, frag-region LDS, pure-MFMA K-loop ----------

__launch_bounds__(256)
__global__ void k_gemm0(const float* __restrict__ X,
                        const unsigned short* __restrict__ Wf,
                        const float* __restrict__ dinv,
                        unsigned short* __restrict__ hs, int N)
{
    __shared__ unsigned short Ah[16 * 512];
    __shared__ unsigned short Al[16 * 512];

    const int tid  = threadIdx.x;
    const int lane = tid & 63, wave = tid >> 6;
    const int mh = wave >> 1, nh = wave & 1;
    const int rowBase = blockIdx.x * 64;
    const int r15 = lane & 15, quad = lane >> 4;

    {
        const int gl = tid >> 4;
        const int f8 = (tid & 15) * 8;
        const int s  = f8 >> 5;
        const int q  = (f8 >> 3) & 3;
        const int lp = q * 16 + gl;
#pragma unroll
        for (int it = 0; it < 4; ++it) {
            int row = rowBase + it * 16 + gl;
            float v[8];
            if (row < N) {
                float4 a0 = *(const float4*)(X + (size_t)row * DH + f8);
                float4 a1 = *(const float4*)(X + (size_t)row * DH + f8 + 4);
                v[0] = a0.x; v[1] = a0.y; v[2] = a0.z; v[3] = a0.w;
                v[4] = a1.x; v[5] = a1.y; v[6] = a1.z; v[7] = a1.w;
            } else {
#pragma unroll
                for (int j = 0; j < 8; ++j) v[j] = 0.f;
            }
            unsigned short hA[8], lA[8];
#pragma unroll
            for (int j = 0; j < 8; ++j) {
                unsigned short h = f2bf(v[j]);
                hA[j] = h; lA[j] = f2bf(v[j] - bf2f(h));
            }
            int reg = it * 4 + s;
            *(ushort4*)(Ah + reg * 512 + lp * 8)     = make_ushort4(hA[0], hA[1], hA[2], hA[3]);
            *(ushort4*)(Ah + reg * 512 + lp * 8 + 4) = make_ushort4(hA[4], hA[5], hA[6], hA[7]);
            *(ushort4*)(Al + reg * 512 + lp * 8)     = make_ushort4(lA[0], lA[1], lA[2], lA[3]);
            *(ushort4*)(Al + reg * 512 + lp * 8 + 4) = make_ushort4(lA[4], lA[5], lA[6], lA[7]);
        }
    }
    __syncthreads();

    f32x4 acc[2][4];
#pragma unroll
    for (int mt = 0; mt < 2; ++mt)
#pragma unroll
        for (int nt = 0; nt < 4; ++nt)
            acc[mt][nt] = (f32x4){0.f, 0.f, 0.f, 0.f};

#pragma unroll
    for (int s = 0; s < 4; ++s) {
        short8 wfh[4], wfl[4];
#pragma unroll
        for (int nt = 0; nt < 4; ++nt) {
            wfh[nt] = *(const short8*)(Wf + ((((nh * 2 + 0) * 4 + s) * 4 + nt) * 512) + lane * 8);
            wfl[nt] = *(const short8*)(Wf + ((((nh * 2 + 1) * 4 + s) * 4 + nt) * 512) + lane * 8);
        }
#pragma unroll
        for (int mt = 0; mt < 2; ++mt) {
            int reg = (mh * 2 + mt) * 4 + s;
            short8 ah = *(const short8*)(Ah + reg * 512 + lane * 8);
            short8 al = *(const short8*)(Al + reg * 512 + lane * 8);
#pragma unroll
            for (int nt = 0; nt < 4; ++nt) {
                acc[mt][nt] = __builtin_amdgcn_mfma_f32_16x16x32_bf16(ah, wfh[nt], acc[mt][nt], 0, 0, 0);
                acc[mt][nt] = __builtin_amdgcn_mfma_f32_16x16x32_bf16(ah, wfl[nt], acc[mt][nt], 0, 0, 0);
                acc[mt][nt] = __builtin_amdgcn_mfma_f32_16x16x32_bf16(al, wfh[nt], acc[mt][nt], 0, 0, 0);
            }
        }
    }

#pragma unroll
    for (int mt = 0; mt < 2; ++mt) {
        int rl = mh * 32 + mt * 16 + quad * 4;
#pragma unroll
        for (int reg = 0; reg < 4; ++reg) {
            int row = rowBase + rl + reg;
            if (row < N) {
                float sc = dinv[row];
#pragma unroll
                for (int nt = 0; nt < 4; ++nt)
                    hs[(size_t)row * DH + nh * 64 + nt * 16 + r15] = f2bf(acc[mt][nt][reg] * sc);
            }
        }
    }
}

// ---------------- fused gather + post + next-layer MFMA GEMM (round-9 best version) --------

__launch_bounds__(256)
__global__ void k_gather_mm(const unsigned short* __restrict__ hs,
                            const int2* __restrict__ rowinfo,
                            const int* __restrict__ csr_src,
                            const float* __restrict__ dinv,
                            const float* __restrict__ cb, const float* __restrict__ bm,
                            const float* __restrict__ bv, const float* __restrict__ bg,
                            const float* __restrict__ bb,
                            const float* __restrict__ prev,
                            float* __restrict__ feat,
                            const unsigned short* __restrict__ Wf,
                            unsigned short* __restrict__ hs_next,
                            int N)
{
    __shared__ unsigned short Ah[16 * LDAP];
    __shared__ unsigned short Al[16 * LDAP];

    const int tid = threadIdx.x;
    const int nb = tid >> 4, lh = tid & 15;
    const int nodeBase = blockIdx.x * 16;
    const int node = nodeBase + nb;
    const int f = lh * 8;

    if (node < N) {
        int2 ri = rowinfo[node];
        const uint4* hsv = (const uint4*)hs;
        float a[8];
        {
            uint4 sv = hsv[(size_t)node * 16 + lh];
            a[0] = blo(sv.x); a[1] = bhi(sv.x); a[2] = blo(sv.y); a[3] = bhi(sv.y);
            a[4] = blo(sv.z); a[5] = bhi(sv.z); a[6] = blo(sv.w); a[7] = bhi(sv.w);
        }
        for (int base = ri.x; base < ri.y; base += 16) {
            int cnt = ri.y - base; if (cnt > 16) cnt = 16;
            int idx = (lh < cnt) ? csr_src[base + lh] : 0;
            int i = 0;
            for (; i + 4 <= cnt; i += 4) {
                int s0 = __shfl(idx, i,     16), s1 = __shfl(idx, i + 1, 16);
                int s2 = __shfl(idx, i + 2, 16), s3 = __shfl(idx, i + 3, 16);
                uint4 v0 = hsv[(size_t)s0 * 16 + lh];
                uint4 v1 = hsv[(size_t)s1 * 16 + lh];
                uint4 v2 = hsv[(size_t)s2 * 16 + lh];
                uint4 v3 = hsv[(size_t)s3 * 16 + lh];
                a[0] += (blo(v0.x) + blo(v1.x)) + (blo(v2.x) + blo(v3.x));
                a[1] += (bhi(v0.x) + bhi(v1.x)) + (bhi(v2.x) + bhi(v3.x));
                a[2] += (blo(v0.y) + blo(v1.y)) + (blo(v2.y) + blo(v3.y));
                a[3] += (bhi(v0.y) + bhi(v1.y)) + (bhi(v2.y) + bhi(v3.y));
                a[4] += (blo(v0.z) + blo(v1.z)) + (blo(v2.z) + blo(v3.z));
                a[5] += (bhi(v0.z) + bhi(v1.z)) + (bhi(v2.z) + bhi(v3.z));
                a[6] += (blo(v0.w) + blo(v1.w)) + (blo(v2.w) + blo(v3.w));
                a[7] += (bhi(v0.w) + bhi(v1.w)) + (bhi(v2.w) + bhi(v3.w));
            }
            for (; i < cnt; ++i) {
                int s = __shfl(idx, i, 16);
                uint4 v = hsv[(size_t)s * 16 + lh];
                a[0] += blo(v.x); a[1] += bhi(v.x); a[2] += blo(v.y); a[3] += bhi(v.y);
                a[4] += blo(v.z); a[5] += bhi(v.z); a[6] += blo(v.w); a[7] += bhi(v.w);
            }
        }

        const float sc = dinv[node];
        float cbv[8], bmv[8], bvv[8], bgv[8], bbv[8];
        *(float4*)cbv = *(const float4*)(cb + f); *(float4*)(cbv + 4) = *(const float4*)(cb + f + 4);
        *(float4*)bmv = *(const float4*)(bm + f); *(float4*)(bmv + 4) = *(const float4*)(bm + f + 4);
        *(float4*)bvv = *(const float4*)(bv + f); *(float4*)(bvv + 4) = *(const float4*)(bv + f + 4);
        *(float4*)bgv = *(const float4*)(bg + f); *(float4*)(bgv + 4) = *(const float4*)(bg + f + 4);
        *(float4*)bbv = *(const float4*)(bb + f); *(float4*)(bbv + 4) = *(const float4*)(bb + f + 4);

        float o[8];
#pragma unroll
        for (int j = 0; j < 8; ++j) {
            float v = (a[j] * sc + cbv[j] - bmv[j]) * rsqrtf(bvv[j] + EPSB) * bgv[j] + bbv[j];
            o[j] = fmaxf(v, 0.f);
        }
        if (prev) {
            float4 p0 = *(const float4*)(prev + (size_t)node * DH + f);
            float4 p1 = *(const float4*)(prev + (size_t)node * DH + f + 4);
            o[0] += p0.x; o[1] += p0.y; o[2] += p0.z; o[3] += p0.w;
            o[4] += p1.x; o[5] += p1.y; o[6] += p1.z; o[7] += p1.w;
        }
        *(float4*)(feat + (size_t)node * DH + f)     = make_float4(o[0], o[1], o[2], o[3]);
        *(float4*)(feat + (size_t)node * DH + f + 4) = make_float4(o[4], o[5], o[6], o[7]);

        unsigned short hA[8], lA[8];
#pragma unroll
        for (int j = 0; j < 8; ++j) {
            unsigned short h = f2bf(o[j]);
            hA[j] = h; lA[j] = f2bf(o[j] - bf2f(h));
        }
        *(ushort4*)(Ah + nb * LDAP + f)     = make_ushort4(hA[0], hA[1], hA[2], hA[3]);
        *(ushort4*)(Ah + nb * LDAP + f + 4) = make_ushort4(hA[4], hA[5], hA[6], hA[7]);
        *(ushort4*)(Al + nb * LDAP + f)     = make_ushort4(lA[0], lA[1], lA[2], lA[3]);
        *(ushort4*)(Al + nb * LDAP + f + 4) = make_ushort4(lA[4], lA[5], lA[6], lA[7]);
    }
    __syncthreads();

    const int lane = tid & 63, wave = tid >> 6;
    const int r15 = lane & 15, quad = lane >> 4;

    f32x4 acc[2];
    acc[0] = (f32x4){0.f, 0.f, 0.f, 0.f};
    acc[1] = (f32x4){0.f, 0.f, 0.f, 0.f};

#pragma unroll
    for (int s = 0; s < 4; ++s) {
        short8 ah = *(const short8*)(Ah + r15 * LDAP + s * 32 + quad * 8);
        short8 al = *(const short8*)(Al + r15 * LDAP + s * 32 + quad * 8);
#pragma unroll
        for (int j = 0; j < 2; ++j) {
            int ntg = wave * 2 + j;
            int nh = ntg >> 2, nt = ntg & 3;
            short8 wh = *(const short8*)(Wf + ((((nh * 2 + 0) * 4 + s) * 4 + nt) * 512) + lane * 8);
            short8 wl = *(const short8*)(Wf + ((((nh * 2 + 1) * 4 + s) * 4 + nt) * 512) + lane * 8);
            acc[j] = __builtin_amdgcn_mfma_f32_16x16x32_bf16(ah, wh, acc[j], 0, 0, 0);
            acc[j] = __builtin_amdgcn_mfma_f32_16x16x32_bf16(ah, wl, acc[j], 0, 0, 0);
            acc[j] = __builtin_amdgcn_mfma_f32_16x16x32_bf16(al, wh, acc[j], 0, 0, 0);
        }
    }

    float dv[4];
#pragma unroll
    for (int reg = 0; reg < 4; ++reg) {
        int row = nodeBase + quad * 4 + reg;
        dv[reg] = (row < N) ? dinv[row] : 0.f;
    }
#pragma unroll
    for (int j = 0; j < 2; ++j) {
        int col = (wave * 2 + j) * 16 + r15;
#pragma unroll
        for (int reg = 0; reg < 4; ++reg) {
            int row = nodeBase + quad * 4 + reg;
            if (row < N)
                hs_next[(size_t)row * DH + col] = f2bf(acc[j][reg] * dv[reg]);
        }
    }
}

// ---------------- final gather + fused POOL: features never hit global ----------------
// Post-activation features are >= 0, so uint atomicMax on float bits is exact and
// zero-init (memset) is a valid identity for both sum and max.

__launch_bounds__(256)
__global__ void k_gather_pool(const unsigned short* __restrict__ hs,
                              const int2* __restrict__ rowinfo,
                              const int* __restrict__ csr_src,
                              const float* __restrict__ dinv,
                              const float* __restrict__ cb, const float* __restrict__ bm,
                              const float* __restrict__ bv, const float* __restrict__ bg,
                              const float* __restrict__ bb,
                              const float* __restrict__ prev,
                              const int* __restrict__ batch,
                              float* __restrict__ sumAcc,       // [G*128]
                              unsigned* __restrict__ maxAcc,    // [G*128]
                              int N)
{
    __shared__ float    ssum[256];    // [seg][feature]
    __shared__ unsigned smax[256];

    const int tid = threadIdx.x;
    const int nb = tid >> 4, lh = tid & 15;
    const int nodeBase = blockIdx.x * 16;
    const int node = nodeBase + nb;
    const int f = lh * 8;

    const int g0 = batch[nodeBase];
    const int g1 = batch[min(nodeBase + 15, N - 1)];

    ssum[tid] = 0.f;
    smax[tid] = 0u;
    __syncthreads();

    if (node < N) {
        int2 ri = rowinfo[node];
        const uint4* hsv = (const uint4*)hs;
        float a[8];
        {
            uint4 sv = hsv[(size_t)node * 16 + lh];
            a[0] = blo(sv.x); a[1] = bhi(sv.x); a[2] = blo(sv.y); a[3] = bhi(sv.y);
            a[4] = blo(sv.z); a[5] = bhi(sv.z); a[6] = blo(sv.w); a[7] = bhi(sv.w);
        }
        for (int base = ri.x; base < ri.y; base += 16) {
            int cnt = ri.y - base; if (cnt > 16) cnt = 16;
            int idx = (lh < cnt) ? csr_src[base + lh] : 0;
            int i = 0;
            for (; i + 4 <= cnt; i += 4) {
                int s0 = __shfl(idx, i,     16), s1 = __shfl(idx, i + 1, 16);
                int s2 = __shfl(idx, i + 2, 16), s3 = __shfl(idx, i + 3, 16);
                uint4 v0 = hsv[(size_t)s0 * 16 + lh];
                uint4 v1 = hsv[(size_t)s1 * 16 + lh];
                uint4 v2 = hsv[(size_t)s2 * 16 + lh];
                uint4 v3 = hsv[(size_t)s3 * 16 + lh];
                a[0] += (blo(v0.x) + blo(v1.x)) + (blo(v2.x) + blo(v3.x));
                a[1] += (bhi(v0.x) + bhi(v1.x)) + (bhi(v2.x) + bhi(v3.x));
                a[2] += (blo(v0.y) + blo(v1.y)) + (blo(v2.y) + blo(v3.y));
                a[3] += (bhi(v0.y) + bhi(v1.y)) + (bhi(v2.y) + bhi(v3.y));
                a[4] += (blo(v0.z) + blo(v1.z)) + (blo(v2.z) + blo(v3.z));
                a[5] += (bhi(v0.z) + bhi(v1.z)) + (bhi(v2.z) + bhi(v3.z));
                a[6] += (blo(v0.w) + blo(v1.w)) + (blo(v2.w) + blo(v3.w));
                a[7] += (bhi(v0.w) + bhi(v1.w)) + (bhi(v2.w) + bhi(v3.w));
            }
            for (; i < cnt; ++i) {
                int s = __shfl(idx, i, 16);
                uint4 v = hsv[(size_t)s * 16 + lh];
                a[0] += blo(v.x); a[1] += bhi(v.x); a[2] += blo(v.y); a[3] += bhi(v.y);
                a[4] += blo(v.z); a[5] += bhi(v.z); a[6] += blo(v.w); a[7] += bhi(v.w);
            }
        }

        const float sc = dinv[node];
        float cbv[8], bmv[8], bvv[8], bgv[8], bbv[8];
        *(float4*)cbv = *(const float4*)(cb + f); *(float4*)(cbv + 4) = *(const float4*)(cb + f + 4);
        *(float4*)bmv = *(const float4*)(bm + f); *(float4*)(bmv + 4) = *(const float4*)(bm + f + 4);
        *(float4*)bvv = *(const float4*)(bv + f); *(float4*)(bvv + 4) = *(const float4*)(bv + f + 4);
        *(float4*)bgv = *(const float4*)(bg + f); *(float4*)(bgv + 4) = *(const float4*)(bg + f + 4);
        *(float4*)bbv = *(const float4*)(bb + f); *(float4*)(bbv + 4) = *(const float4*)(bb + f + 4);

        float4 p0 = *(const float4*)(prev + (size_t)node * DH + f);
        float4 p1 = *(const float4*)(prev + (size_t)node * DH + f + 4);
        float o[8];
#pragma unroll
        for (int j = 0; j < 8; ++j) {
            float v = (a[j] * sc + cbv[j] - bmv[j]) * rsqrtf(bvv[j] + EPSB) * bgv[j] + bbv[j];
            o[j] = fmaxf(v, 0.f);
        }
        o[0] += p0.x; o[1] += p0.y; o[2] += p0.z; o[3] += p0.w;
        o[4] += p1.x; o[5] += p1.y; o[6] += p1.z; o[7] += p1.w;

        const int seg = (batch[node] != g0) ? 1 : 0;
        float*    sp = ssum + seg * 128 + f;
        unsigned* mp = smax + seg * 128 + f;
#pragma unroll
        for (int j = 0; j < 8; ++j) {
            atomicAdd(&sp[j], o[j]);
            atomicMax(&mp[j], __float_as_uint(o[j]));
        }
    }
    __syncthreads();

    // flush segments to global accumulators (one thread per [seg][feature] entry)
    const int seg = tid >> 7, fi = tid & 127;
    if (seg == 0 || g1 != g0) {
        int g = g0 + seg;
        atomicAdd(&sumAcc[(size_t)g * 128 + fi], ssum[tid]);
        atomicMax(&maxAcc[(size_t)g * 128 + fi], smax[tid]);
    }
}

// ---------------- MLP head: reads pooled accumulators ----------------

__launch_bounds__(128)
__global__ void k_head(const float* __restrict__ sumAcc, const unsigned* __restrict__ maxAcc,
                       const int* __restrict__ starts,
                       const float* __restrict__ L1w, const float* __restrict__ L1b,
                       const float* __restrict__ L2w, const float* __restrict__ L2b,
                       const float* __restrict__ L3w, const float* __restrict__ L3b,
                       float* __restrict__ out)
{
    int g = blockIdx.x, t = threadIdx.x;
    float cnt = (float)(starts[g + 1] - starts[g]);

    __shared__ float h[256];
    h[t]       = sumAcc[(size_t)g * 128 + t] / cnt;
    h[128 + t] = __uint_as_float(maxAcc[(size_t)g * 128 + t]);
    __syncthreads();

    float a = L1b[t];
    for (int k = 0; k < 256; ++k) a += h[k] * L1w[k * DH + t];
    __shared__ float h1[128];
    h1[t] = fmaxf(a, 0.f);
    __syncthreads();

    __shared__ float h2[64];
    if (t < 64) {
        float a2 = L2b[t];
        for (int k = 0; k < 128; ++k) a2 += h1[k] * L2w[k * 64 + t];
        h2[t] = fmaxf(a2, 0.f);
    }
    __syncthreads();

    if (t < 64) {
        float p = h2[t] * L3w[t];
#pragma unroll
        for (int off = 32; off > 0; off >>= 1) p += __shfl_down(p, off, 64);
        if (t == 0) out[g] = p + L3b[0];
    }
}

// ---------------- launch ----------------

static inline char* align16(char* p) {
    return (char*)(((uintptr_t)p + 15) & ~(uintptr_t)15);
}

extern "C" void kernel_launch(void* const* d_in, const int* in_sizes, int n_in,
                              void* d_out, int out_size, void* d_ws, size_t ws_size,
                              hipStream_t stream)
{
    const float* x     = (const float*)d_in[0];
    const int*   ei    = (const int*)d_in[1];
    const int*   batch = (const int*)d_in[2];
    const int N = in_sizes[0] / DH;
    const int E = in_sizes[1] / 2;
    const int G = out_size;
    const int* src = ei;
    const int* dst = ei + E;

    const float* W[3]  = {(const float*)d_in[3],  (const float*)d_in[9],  (const float*)d_in[15]};
    const float* cb[3] = {(const float*)d_in[4],  (const float*)d_in[10], (const float*)d_in[16]};
    const float* bg[3] = {(const float*)d_in[5],  (const float*)d_in[11], (const float*)d_in[17]};
    const float* bt[3] = {(const float*)d_in[6],  (const float*)d_in[12], (const float*)d_in[18]};
    const float* bm[3] = {(const float*)d_in[7],  (const float*)d_in[13], (const float*)d_in[19]};
    const float* bv[3] = {(const float*)d_in[8],  (const float*)d_in[14], (const float*)d_in[20]};
    const float* L1w = (const float*)d_in[21]; const float* L1b = (const float*)d_in[22];
    const float* L2w = (const float*)d_in[23]; const float* L2b = (const float*)d_in[24];
    const float* L3w = (const float*)d_in[25]; const float* L3b = (const float*)d_in[26];

    char* wsp = (char*)d_ws;
    size_t featB = (size_t)N * DH * sizeof(float);
    size_t hsB   = (size_t)N * DH * sizeof(unsigned short);
    float* F_A = (float*)wsp; wsp += featB;
    float* F_B = (float*)wsp; wsp += featB;
    unsigned short* HS0 = (unsigned short*)F_B;              // alias: dead before F_B written
    unsigned short* HS1 = (unsigned short*)wsp; wsp += hsB;
    unsigned short* HS2 = (unsigned short*)wsp; wsp += hsB;
    unsigned short* Wfrag = (unsigned short*)wsp; wsp += 3 * 65536;
    int2*  rowinfo = (int2*)wsp;  wsp += (size_t)N * sizeof(int2);
    float* dinv    = (float*)wsp; wsp += (size_t)N * sizeof(float);
    int*   starts  = (int*)wsp;   wsp = align16(wsp + (size_t)(G + 1) * sizeof(int));
    // zeroed region: gcur + sumAcc + maxAcc (single memset)
    int*      gcur   = (int*)wsp;      wsp += (size_t)MAXB * sizeof(int);
    float*    sumAcc = (float*)wsp;    wsp += (size_t)G * 128 * sizeof(float);
    unsigned* maxAcc = (unsigned*)wsp; wsp += (size_t)G * 128 * sizeof(unsigned);
    size_t zeroBytes = (size_t)MAXB * sizeof(int) + (size_t)G * 128 * 8;
    int*   bbuf    = (int*)align16(wsp); wsp = (char*)bbuf + (size_t)MAXB * BCAP * sizeof(int);

    const int NB = (N + 127) >> 7;
    const int nblkA = 512;
    const int chunk = (E + nblkA - 1) / nblkA;

    hipMemsetAsync(gcur, 0, zeroBytes, stream);
    k_bucketA<<<nblkA + 48, 256, 0, stream>>>(src, dst, gcur, bbuf, batch, starts,
                                              W[0], W[1], W[2], Wfrag,
                                              E, NB, chunk, N, G);
    k_bfinal <<<NB, 256, 0, stream>>>(gcur, bbuf, rowinfo, dinv, N);

    int gemmGrid = (N + 63) / 64;
    int gathGrid = (N + 15) / 16;

    k_gemm0<<<gemmGrid, 256, 0, stream>>>(x, Wfrag, dinv, HS0, N);
    k_gather_mm<<<gathGrid, 256, 0, stream>>>(HS0, rowinfo, bbuf, dinv,
                                              cb[0], bm[0], bv[0], bg[0], bt[0],
                                              nullptr, F_A, Wfrag + 32768, HS1, N);
    k_gather_mm<<<gathGrid, 256, 0, stream>>>(HS1, rowinfo, bbuf, dinv,
                                              cb[1], bm[1], bv[1], bg[1], bt[1],
                                              F_A, F_B, Wfrag + 65536, HS2, N);
    k_gather_pool<<<gathGrid, 256, 0, stream>>>(HS2, rowinfo, bbuf, dinv,
                                                cb[2], bm[2], bv[2], bg[2], bt[2],
                                                F_B, batch, sumAcc, maxAcc, N);

    k_head<<<G, 128, 0, stream>>>(sumAcc, maxAcc, starts,
                                  L1w, L1b, L2w, L2b, L3w, L3b, (float*)d_out);
}

// Round 12
// 466.640 us; speedup vs baseline: 1.0733x; 1.0733x over previous
//
#include <hip/hip_runtime.h>
#include <math.h>

#define DH 128
#define EPSB 1e-5f
#define MAXB 832     // max buckets (N <= 106496)
#define BCAP 2560    // bucket capacity (mean ~2046 at E/N=16, +11 sigma)
#define LDAP 136     // padded LDS row stride (ushorts)

typedef __attribute__((ext_vector_type(8))) short short8;
typedef __attribute__((ext_vector_type(4))) float f32x4;

static __device__ __forceinline__ unsigned short f2bf(float f) {
    unsigned u = __float_as_uint(f);
    u += 0x7fffu + ((u >> 16) & 1u);
    return (unsigned short)(u >> 16);
}
static __device__ __forceinline__ float bf2f(unsigned short h) {
    return __uint_as_float(((unsigned)h) << 16);
}
static __device__ __forceinline__ float blo(unsigned u) { return __uint_as_float(u << 16); }
static __device__ __forceinline__ float bhi(unsigned u) { return __uint_as_float(u & 0xFFFF0000u); }

// ---------------- pass A: edge bucketing + graph bounds + W fragmentize ----------------

__launch_bounds__(256)
__global__ void k_bucketA(const int* __restrict__ src, const int* __restrict__ dst,
                          int* __restrict__ gcur, int* __restrict__ bbuf,
                          const int* __restrict__ batch, int* __restrict__ starts,
                          const float* __restrict__ W0, const float* __restrict__ W1,
                          const float* __restrict__ W2, unsigned short* __restrict__ Wf0,
                          int E, int NB, int chunk, int N, int G)
{
    const int t = threadIdx.x;

    if (blockIdx.x >= 512) {            // ---- W fragmentize ----
        int fid = (blockIdx.x - 512) * 4 + (t >> 6);   // 0..191
        int lane = t & 63;
        int l = fid >> 6, f = fid & 63;
        const float* W = (l == 0) ? W0 : (l == 1) ? W1 : W2;
        unsigned short* Wf = Wf0 + (size_t)l * 32768;
        int nt = f & 3, s = (f >> 2) & 3, p = (f >> 4) & 1, nh = f >> 5;
        int n = nh * 64 + nt * 16 + (lane & 15);
        int kbase = s * 32 + (lane >> 4) * 8;
        unsigned short o[8];
#pragma unroll
        for (int j = 0; j < 8; ++j) {
            float w = W[(size_t)(kbase + j) * DH + n];
            unsigned short h = f2bf(w);
            o[j] = p ? f2bf(w - bf2f(h)) : h;
        }
        unsigned short* d = Wf + (size_t)f * 512 + lane * 8;
        *(ushort4*)d       = make_ushort4(o[0], o[1], o[2], o[3]);
        *(ushort4*)(d + 4) = make_ushort4(o[4], o[5], o[6], o[7]);
        return;
    }

    __shared__ int cnt[MAXB];
    __shared__ int base[MAXB];

    for (int i = blockIdx.x * 256 + t; i < N; i += 512 * 256) {
        int b = batch[i];
        if (i == 0) { starts[0] = 0; starts[G] = N; }
        else if (batch[i - 1] != b) starts[b] = i;
    }

    for (int i = t; i < NB; i += 256) cnt[i] = 0;
    __syncthreads();
    const int e0 = blockIdx.x * chunk;
    const int e1 = min(E, e0 + chunk);
    for (int e = e0 + t; e < e1; e += 256)
        atomicAdd(&cnt[dst[e] >> 7], 1);
    __syncthreads();
    for (int i = t; i < NB; i += 256) {
        int c = cnt[i];
        base[i] = (c > 0) ? atomicAdd(&gcur[i], c) : 0;
        cnt[i] = 0;
    }
    __syncthreads();
    for (int e = e0 + t; e < e1; e += 256) {
        int d = dst[e];
        int b = d >> 7;
        int o = base[b] + atomicAdd(&cnt[b], 1);
        if (o < BCAP) bbuf[(size_t)b * BCAP + o] = (src[e] << 7) | (d & 127);
    }
}

// ---------------- pass B: per-bucket deg/dinv/rowinfo + in-place csr scatter ----------------

__launch_bounds__(256)
__global__ void k_bfinal(const int* __restrict__ gcur, int* __restrict__ bbuf,
                         int2* __restrict__ rowinfo, float* __restrict__ dinv, int N)
{
    __shared__ int ebuf[BCAP];
    __shared__ int dcnt[128];
    __shared__ int sp[128];
    const int b = blockIdx.x, t = threadIdx.x;
    const int c = min(gcur[b], BCAP);
    const int base = b * BCAP;
    int* p = bbuf + base;
    for (int i = t; i < c; i += 256) ebuf[i] = p[i];
    if (t < 128) dcnt[t] = 0;
    __syncthreads();
    for (int i = t; i < c; i += 256) atomicAdd(&dcnt[ebuf[i] & 127], 1);
    __syncthreads();
    if (t < 128) sp[t] = dcnt[t];
    __syncthreads();
    for (int off = 1; off < 128; off <<= 1) {
        int u = (t < 128 && t >= off) ? sp[t - off] : 0;
        __syncthreads();
        if (t < 128) sp[t] += u;
        __syncthreads();
    }
    if (t < 128) {
        sp[t] -= dcnt[t];
        int d = b * 128 + t;
        if (d < N) {
            rowinfo[d] = make_int2(base + sp[t], base + sp[t] + dcnt[t]);
            dinv[d] = rsqrtf((float)(dcnt[t] + 1));
        }
        dcnt[t] = 0;
    }
    __syncthreads();
    for (int i = t; i < c; i += 256) {
        int e = ebuf[i];
        int dl = e & 127;
        int o = atomicAdd(&dcnt[dl], 1);
        p[sp[dl] + o] = e >> 7;
    }
}

// ---------------- GEMM layer 0: split at staging, frag-region LDS, pure-MFMA K-loop ----------

__launch_bounds__(256)
__global__ void k_gemm0(const float* __restrict__ X,
                        const unsigned short* __restrict__ Wf,
                        const float* __restrict__ dinv,
                        unsigned short* __restrict__ hs, int N)
{
    __shared__ unsigned short Ah[16 * 512];
    __shared__ unsigned short Al[16 * 512];

    const int tid  = threadIdx.x;
    const int lane = tid & 63, wave = tid >> 6;
    const int mh = wave >> 1, nh = wave & 1;
    const int rowBase = blockIdx.x * 64;
    const int r15 = lane & 15, quad = lane >> 4;

    {
        const int gl = tid >> 4;
        const int f8 = (tid & 15) * 8;
        const int s  = f8 >> 5;
        const int q  = (f8 >> 3) & 3;
        const int lp = q * 16 + gl;
#pragma unroll
        for (int it = 0; it < 4; ++it) {
            int row = rowBase + it * 16 + gl;
            float v[8];
            if (row < N) {
                float4 a0 = *(const float4*)(X + (size_t)row * DH + f8);
                float4 a1 = *(const float4*)(X + (size_t)row * DH + f8 + 4);
                v[0] = a0.x; v[1] = a0.y; v[2] = a0.z; v[3] = a0.w;
                v[4] = a1.x; v[5] = a1.y; v[6] = a1.z; v[7] = a1.w;
            } else {
#pragma unroll
                for (int j = 0; j < 8; ++j) v[j] = 0.f;
            }
            unsigned short hA[8], lA[8];
#pragma unroll
            for (int j = 0; j < 8; ++j) {
                unsigned short h = f2bf(v[j]);
                hA[j] = h; lA[j] = f2bf(v[j] - bf2f(h));
            }
            int reg = it * 4 + s;
            *(ushort4*)(Ah + reg * 512 + lp * 8)     = make_ushort4(hA[0], hA[1], hA[2], hA[3]);
            *(ushort4*)(Ah + reg * 512 + lp * 8 + 4) = make_ushort4(hA[4], hA[5], hA[6], hA[7]);
            *(ushort4*)(Al + reg * 512 + lp * 8)     = make_ushort4(lA[0], lA[1], lA[2], lA[3]);
            *(ushort4*)(Al + reg * 512 + lp * 8 + 4) = make_ushort4(lA[4], lA[5], lA[6], lA[7]);
        }
    }
    __syncthreads();

    f32x4 acc[2][4];
#pragma unroll
    for (int mt = 0; mt < 2; ++mt)
#pragma unroll
        for (int nt = 0; nt < 4; ++nt)
            acc[mt][nt] = (f32x4){0.f, 0.f, 0.f, 0.f};

#pragma unroll
    for (int s = 0; s < 4; ++s) {
        short8 wfh[4], wfl[4];
#pragma unroll
        for (int nt = 0; nt < 4; ++nt) {
            wfh[nt] = *(const short8*)(Wf + ((((nh * 2 + 0) * 4 + s) * 4 + nt) * 512) + lane * 8);
            wfl[nt] = *(const short8*)(Wf + ((((nh * 2 + 1) * 4 + s) * 4 + nt) * 512) + lane * 8);
        }
#pragma unroll
        for (int mt = 0; mt < 2; ++mt) {
            int reg = (mh * 2 + mt) * 4 + s;
            short8 ah = *(const short8*)(Ah + reg * 512 + lane * 8);
            short8 al = *(const short8*)(Al + reg * 512 + lane * 8);
#pragma unroll
            for (int nt = 0; nt < 4; ++nt) {
                acc[mt][nt] = __builtin_amdgcn_mfma_f32_16x16x32_bf16(ah, wfh[nt], acc[mt][nt], 0, 0, 0);
                acc[mt][nt] = __builtin_amdgcn_mfma_f32_16x16x32_bf16(ah, wfl[nt], acc[mt][nt], 0, 0, 0);
                acc[mt][nt] = __builtin_amdgcn_mfma_f32_16x16x32_bf16(al, wfh[nt], acc[mt][nt], 0, 0, 0);
            }
        }
    }

#pragma unroll
    for (int mt = 0; mt < 2; ++mt) {
        int rl = mh * 32 + mt * 16 + quad * 4;
#pragma unroll
        for (int reg = 0; reg < 4; ++reg) {
            int row = rowBase + rl + reg;
            if (row < N) {
                float sc = dinv[row];
#pragma unroll
                for (int nt = 0; nt < 4; ++nt)
                    hs[(size_t)row * DH + nh * 64 + nt * 16 + r15] = f2bf(acc[mt][nt][reg] * sc);
            }
        }
    }
}

// ---------------- fused gather + post + next-layer MFMA GEMM (round-9 best version) --------

__launch_bounds__(256)
__global__ void k_gather_mm(const unsigned short* __restrict__ hs,
                            const int2* __restrict__ rowinfo,
                            const int* __restrict__ csr_src,
                            const float* __restrict__ dinv,
                            const float* __restrict__ cb, const float* __restrict__ bm,
                            const float* __restrict__ bv, const float* __restrict__ bg,
                            const float* __restrict__ bb,
                            const float* __restrict__ prev,
                            float* __restrict__ feat,
                            const unsigned short* __restrict__ Wf,
                            unsigned short* __restrict__ hs_next,
                            int N)
{
    __shared__ unsigned short Ah[16 * LDAP];
    __shared__ unsigned short Al[16 * LDAP];

    const int tid = threadIdx.x;
    const int nb = tid >> 4, lh = tid & 15;
    const int nodeBase = blockIdx.x * 16;
    const int node = nodeBase + nb;
    const int f = lh * 8;

    if (node < N) {
        int2 ri = rowinfo[node];
        const uint4* hsv = (const uint4*)hs;
        float a[8];
        {
            uint4 sv = hsv[(size_t)node * 16 + lh];
            a[0] = blo(sv.x); a[1] = bhi(sv.x); a[2] = blo(sv.y); a[3] = bhi(sv.y);
            a[4] = blo(sv.z); a[5] = bhi(sv.z); a[6] = blo(sv.w); a[7] = bhi(sv.w);
        }
        for (int base = ri.x; base < ri.y; base += 16) {
            int cnt = ri.y - base; if (cnt > 16) cnt = 16;
            int idx = (lh < cnt) ? csr_src[base + lh] : 0;
            int i = 0;
            for (; i + 4 <= cnt; i += 4) {
                int s0 = __shfl(idx, i,     16), s1 = __shfl(idx, i + 1, 16);
                int s2 = __shfl(idx, i + 2, 16), s3 = __shfl(idx, i + 3, 16);
                uint4 v0 = hsv[(size_t)s0 * 16 + lh];
                uint4 v1 = hsv[(size_t)s1 * 16 + lh];
                uint4 v2 = hsv[(size_t)s2 * 16 + lh];
                uint4 v3 = hsv[(size_t)s3 * 16 + lh];
                a[0] += (blo(v0.x) + blo(v1.x)) + (blo(v2.x) + blo(v3.x));
                a[1] += (bhi(v0.x) + bhi(v1.x)) + (bhi(v2.x) + bhi(v3.x));
                a[2] += (blo(v0.y) + blo(v1.y)) + (blo(v2.y) + blo(v3.y));
                a[3] += (bhi(v0.y) + bhi(v1.y)) + (bhi(v2.y) + bhi(v3.y));
                a[4] += (blo(v0.z) + blo(v1.z)) + (blo(v2.z) + blo(v3.z));
                a[5] += (bhi(v0.z) + bhi(v1.z)) + (bhi(v2.z) + bhi(v3.z));
                a[6] += (blo(v0.w) + blo(v1.w)) + (blo(v2.w) + blo(v3.w));
                a[7] += (bhi(v0.w) + bhi(v1.w)) + (bhi(v2.w) + bhi(v3.w));
            }
            for (; i < cnt; ++i) {
                int s = __shfl(idx, i, 16);
                uint4 v = hsv[(size_t)s * 16 + lh];
                a[0] += blo(v.x); a[1] += bhi(v.x); a[2] += blo(v.y); a[3] += bhi(v.y);
                a[4] += blo(v.z); a[5] += bhi(v.z); a[6] += blo(v.w); a[7] += bhi(v.w);
            }
        }

        const float sc = dinv[node];
        float cbv[8], bmv[8], bvv[8], bgv[8], bbv[8];
        *(float4*)cbv = *(const float4*)(cb + f); *(float4*)(cbv + 4) = *(const float4*)(cb + f + 4);
        *(float4*)bmv = *(const float4*)(bm + f); *(float4*)(bmv + 4) = *(const float4*)(bm + f + 4);
        *(float4*)bvv = *(const float4*)(bv + f); *(float4*)(bvv + 4) = *(const float4*)(bv + f + 4);
        *(float4*)bgv = *(const float4*)(bg + f); *(float4*)(bgv + 4) = *(const float4*)(bg + f + 4);
        *(float4*)bbv = *(const float4*)(bb + f); *(float4*)(bbv + 4) = *(const float4*)(bb + f + 4);

        float o[8];
#pragma unroll
        for (int j = 0; j < 8; ++j) {
            float v = (a[j] * sc + cbv[j] - bmv[j]) * rsqrtf(bvv[j] + EPSB) * bgv[j] + bbv[j];
            o[j] = fmaxf(v, 0.f);
        }
        if (prev) {
            float4 p0 = *(const float4*)(prev + (size_t)node * DH + f);
            float4 p1 = *(const float4*)(prev + (size_t)node * DH + f + 4);
            o[0] += p0.x; o[1] += p0.y; o[2] += p0.z; o[3] += p0.w;
            o[4] += p1.x; o[5] += p1.y; o[6] += p1.z; o[7] += p1.w;
        }
        *(float4*)(feat + (size_t)node * DH + f)     = make_float4(o[0], o[1], o[2], o[3]);
        *(float4*)(feat + (size_t)node * DH + f + 4) = make_float4(o[4], o[5], o[6], o[7]);

        unsigned short hA[8], lA[8];
#pragma unroll
        for (int j = 0; j < 8; ++j) {
            unsigned short h = f2bf(o[j]);
            hA[j] = h; lA[j] = f2bf(o[j] - bf2f(h));
        }
        *(ushort4*)(Ah + nb * LDAP + f)     = make_ushort4(hA[0], hA[1], hA[2], hA[3]);
        *(ushort4*)(Ah + nb * LDAP + f + 4) = make_ushort4(hA[4], hA[5], hA[6], hA[7]);
        *(ushort4*)(Al + nb * LDAP + f)     = make_ushort4(lA[0], lA[1], lA[2], lA[3]);
        *(ushort4*)(Al + nb * LDAP + f + 4) = make_ushort4(lA[4], lA[5], lA[6], lA[7]);
    }
    __syncthreads();

    const int lane = tid & 63, wave = tid >> 6;
    const int r15 = lane & 15, quad = lane >> 4;

    f32x4 acc[2];
    acc[0] = (f32x4){0.f, 0.f, 0.f, 0.f};
    acc[1] = (f32x4){0.f, 0.f, 0.f, 0.f};

#pragma unroll
    for (int s = 0; s < 4; ++s) {
        short8 ah = *(const short8*)(Ah + r15 * LDAP + s * 32 + quad * 8);
        short8 al = *(const short8*)(Al + r15 * LDAP + s * 32 + quad * 8);
#pragma unroll
        for (int j = 0; j < 2; ++j) {
            int ntg = wave * 2 + j;
            int nh = ntg >> 2, nt = ntg & 3;
            short8 wh = *(const short8*)(Wf + ((((nh * 2 + 0) * 4 + s) * 4 + nt) * 512) + lane * 8);
            short8 wl = *(const short8*)(Wf + ((((nh * 2 + 1) * 4 + s) * 4 + nt) * 512) + lane * 8);
            acc[j] = __builtin_amdgcn_mfma_f32_16x16x32_bf16(ah, wh, acc[j], 0, 0, 0);
            acc[j] = __builtin_amdgcn_mfma_f32_16x16x32_bf16(ah, wl, acc[j], 0, 0, 0);
            acc[j] = __builtin_amdgcn_mfma_f32_16x16x32_bf16(al, wh, acc[j], 0, 0, 0);
        }
    }

    float dv[4];
#pragma unroll
    for (int reg = 0; reg < 4; ++reg) {
        int row = nodeBase + quad * 4 + reg;
        dv[reg] = (row < N) ? dinv[row] : 0.f;
    }
#pragma unroll
    for (int j = 0; j < 2; ++j) {
        int col = (wave * 2 + j) * 16 + r15;
#pragma unroll
        for (int reg = 0; reg < 4; ++reg) {
            int row = nodeBase + quad * 4 + reg;
            if (row < N)
                hs_next[(size_t)row * DH + col] = f2bf(acc[j][reg] * dv[reg]);
        }
    }
}

// ---------------- final gather + fused POOL (staged tree reduction, no LDS atomics) --------
// Features >= 0 (post-ReLU + nonneg residual), so max identity 0 is exact and zero-init
// global accumulators (memset) are valid for both sum and max.

__launch_bounds__(256)
__global__ void k_gather_pool(const unsigned short* __restrict__ hs,
                              const int2* __restrict__ rowinfo,
                              const int* __restrict__ csr_src,
                              const float* __restrict__ dinv,
                              const float* __restrict__ cb, const float* __restrict__ bm,
                              const float* __restrict__ bv, const float* __restrict__ bg,
                              const float* __restrict__ bb,
                              const float* __restrict__ prev,
                              const int* __restrict__ batch,
                              float* __restrict__ sumAcc,       // [G*128]
                              unsigned* __restrict__ maxAcc,    // [G*128]
                              int N)
{
    __shared__ float fsh[16][128];      // 8 KB: per-node features
    __shared__ float psum[2][2][128];   // 4 KB: [half][seg][feature]
    __shared__ float pmax[2][2][128];   // 4 KB
    __shared__ int   sb[16];            // segment flag per node row

    const int tid = threadIdx.x;
    const int nb = tid >> 4, lh = tid & 15;
    const int nodeBase = blockIdx.x * 16;
    const int node = nodeBase + nb;
    const int f = lh * 8;

    const int g0 = batch[nodeBase];
    const int g1 = batch[min(nodeBase + 15, N - 1)];

    if (tid < 16) {
        int nn = nodeBase + tid;
        sb[tid] = (nn < N && batch[nn] != g0) ? 1 : 0;
    }
    if (nodeBase + 16 > N) {   // tail block: zero rows beyond N
        if (node >= N) {
#pragma unroll
            for (int j = 0; j < 8; ++j) fsh[nb][f + j] = 0.f;
        }
    }

    if (node < N) {
        int2 ri = rowinfo[node];
        const uint4* hsv = (const uint4*)hs;
        float a[8];
        {
            uint4 sv = hsv[(size_t)node * 16 + lh];
            a[0] = blo(sv.x); a[1] = bhi(sv.x); a[2] = blo(sv.y); a[3] = bhi(sv.y);
            a[4] = blo(sv.z); a[5] = bhi(sv.z); a[6] = blo(sv.w); a[7] = bhi(sv.w);
        }
        for (int base = ri.x; base < ri.y; base += 16) {
            int cnt = ri.y - base; if (cnt > 16) cnt = 16;
            int idx = (lh < cnt) ? csr_src[base + lh] : 0;
            int i = 0;
            for (; i + 4 <= cnt; i += 4) {
                int s0 = __shfl(idx, i,     16), s1 = __shfl(idx, i + 1, 16);
                int s2 = __shfl(idx, i + 2, 16), s3 = __shfl(idx, i + 3, 16);
                uint4 v0 = hsv[(size_t)s0 * 16 + lh];
                uint4 v1 = hsv[(size_t)s1 * 16 + lh];
                uint4 v2 = hsv[(size_t)s2 * 16 + lh];
                uint4 v3 = hsv[(size_t)s3 * 16 + lh];
                a[0] += (blo(v0.x) + blo(v1.x)) + (blo(v2.x) + blo(v3.x));
                a[1] += (bhi(v0.x) + bhi(v1.x)) + (bhi(v2.x) + bhi(v3.x));
                a[2] += (blo(v0.y) + blo(v1.y)) + (blo(v2.y) + blo(v3.y));
                a[3] += (bhi(v0.y) + bhi(v1.y)) + (bhi(v2.y) + bhi(v3.y));
                a[4] += (blo(v0.z) + blo(v1.z)) + (blo(v2.z) + blo(v3.z));
                a[5] += (bhi(v0.z) + bhi(v1.z)) + (bhi(v2.z) + bhi(v3.z));
                a[6] += (blo(v0.w) + blo(v1.w)) + (blo(v2.w) + blo(v3.w));
                a[7] += (bhi(v0.w) + bhi(v1.w)) + (bhi(v2.w) + bhi(v3.w));
            }
            for (; i < cnt; ++i) {
                int s = __shfl(idx, i, 16);
                uint4 v = hsv[(size_t)s * 16 + lh];
                a[0] += blo(v.x); a[1] += bhi(v.x); a[2] += blo(v.y); a[3] += bhi(v.y);
                a[4] += blo(v.z); a[5] += bhi(v.z); a[6] += blo(v.w); a[7] += bhi(v.w);
            }
        }

        const float sc = dinv[node];
        float cbv[8], bmv[8], bvv[8], bgv[8], bbv[8];
        *(float4*)cbv = *(const float4*)(cb + f); *(float4*)(cbv + 4) = *(const float4*)(cb + f + 4);
        *(float4*)bmv = *(const float4*)(bm + f); *(float4*)(bmv + 4) = *(const float4*)(bm + f + 4);
        *(float4*)bvv = *(const float4*)(bv + f); *(float4*)(bvv + 4) = *(const float4*)(bv + f + 4);
        *(float4*)bgv = *(const float4*)(bg + f); *(float4*)(bgv + 4) = *(const float4*)(bg + f + 4);
        *(float4*)bbv = *(const float4*)(bb + f); *(float4*)(bbv + 4) = *(const float4*)(bb + f + 4);

        float4 p0 = *(const float4*)(prev + (size_t)node * DH + f);
        float4 p1 = *(const float4*)(prev + (size_t)node * DH + f + 4);
        float o[8];
#pragma unroll
        for (int j = 0; j < 8; ++j) {
            float v = (a[j] * sc + cbv[j] - bmv[j]) * rsqrtf(bvv[j] + EPSB) * bgv[j] + bbv[j];
            o[j] = fmaxf(v, 0.f);
        }
        o[0] += p0.x; o[1] += p0.y; o[2] += p0.z; o[3] += p0.w;
        o[4] += p1.x; o[5] += p1.y; o[6] += p1.z; o[7] += p1.w;

        *(float4*)(&fsh[nb][f])     = make_float4(o[0], o[1], o[2], o[3]);
        *(float4*)(&fsh[nb][f + 4]) = make_float4(o[4], o[5], o[6], o[7]);
    }
    __syncthreads();

    // ---- reduction: thread (half, fi) reduces 8 rows of feature fi ----
    const int half = tid >> 7;          // 0: rows 0-7, 1: rows 8-15
    const int fi = tid & 127;
    float s0 = 0.f, s1 = 0.f, m0 = 0.f, m1 = 0.f;
#pragma unroll
    for (int r = 0; r < 8; ++r) {
        int row = half * 8 + r;
        float v = fsh[row][fi];
        if (sb[row]) { s1 += v; m1 = fmaxf(m1, v); }
        else         { s0 += v; m0 = fmaxf(m0, v); }
    }
    psum[half][0][fi] = s0; psum[half][1][fi] = s1;
    pmax[half][0][fi] = m0; pmax[half][1][fi] = m1;
    __syncthreads();

    if (half == 0) {
        float ts0 = psum[0][0][fi] + psum[1][0][fi];
        float tm0 = fmaxf(pmax[0][0][fi], pmax[1][0][fi]);
        unsafeAtomicAdd(&sumAcc[(size_t)g0 * 128 + fi], ts0);
        atomicMax(&maxAcc[(size_t)g0 * 128 + fi], __float_as_uint(tm0));
        if (g1 != g0) {
            float ts1 = psum[0][1][fi] + psum[1][1][fi];
            float tm1 = fmaxf(pmax[0][1][fi], pmax[1][1][fi]);
            unsafeAtomicAdd(&sumAcc[(size_t)g1 * 128 + fi], ts1);
            atomicMax(&maxAcc[(size_t)g1 * 128 + fi], __float_as_uint(tm1));
        }
    }
}

// ---------------- MLP head: reads pooled accumulators ----------------

__launch_bounds__(128)
__global__ void k_head(const float* __restrict__ sumAcc, const unsigned* __restrict__ maxAcc,
                       const int* __restrict__ starts,
                       const float* __restrict__ L1w, const float* __restrict__ L1b,
                       const float* __restrict__ L2w, const float* __restrict__ L2b,
                       const float* __restrict__ L3w, const float* __restrict__ L3b,
                       float* __restrict__ out)
{
    int g = blockIdx.x, t = threadIdx.x;
    float cnt = (float)(starts[g + 1] - starts[g]);

    __shared__ float h[256];
    h[t]       = sumAcc[(size_t)g * 128 + t] / cnt;
    h[128 + t] = __uint_as_float(maxAcc[(size_t)g * 128 + t]);
    __syncthreads();

    float a = L1b[t];
    for (int k = 0; k < 256; ++k) a += h[k] * L1w[k * DH + t];
    __shared__ float h1[128];
    h1[t] = fmaxf(a, 0.f);
    __syncthreads();

    __shared__ float h2[64];
    if (t < 64) {
        float a2 = L2b[t];
        for (int k = 0; k < 128; ++k) a2 += h1[k] * L2w[k * 64 + t];
        h2[t] = fmaxf(a2, 0.f);
    }
    __syncthreads();

    if (t < 64) {
        float p = h2[t] * L3w[t];
#pragma unroll
        for (int off = 32; off > 0; off >>= 1) p += __shfl_down(p, off, 64);
        if (t == 0) out[g] = p + L3b[0];
    }
}

// ---------------- launch ----------------

static inline char* align16(char* p) {
    return (char*)(((uintptr_t)p + 15) & ~(uintptr_t)15);
}

extern "C" void kernel_launch(void* const* d_in, const int* in_sizes, int n_in,
                              void* d_out, int out_size, void* d_ws, size_t ws_size,
                              hipStream_t stream)
{
    const float* x     = (const float*)d_in[0];
    const int*   ei    = (const int*)d_in[1];
    const int*   batch = (const int*)d_in[2];
    const int N = in_sizes[0] / DH;
    const int E = in_sizes[1] / 2;
    const int G = out_size;
    const int* src = ei;
    const int* dst = ei + E;

    const float* W[3]  = {(const float*)d_in[3],  (const float*)d_in[9],  (const float*)d_in[15]};
    const float* cb[3] = {(const float*)d_in[4],  (const float*)d_in[10], (const float*)d_in[16]};
    const float* bg[3] = {(const float*)d_in[5],  (const float*)d_in[11], (const float*)d_in[17]};
    const float* bt[3] = {(const float*)d_in[6],  (const float*)d_in[12], (const float*)d_in[18]};
    const float* bm[3] = {(const float*)d_in[7],  (const float*)d_in[13], (const float*)d_in[19]};
    const float* bv[3] = {(const float*)d_in[8],  (const float*)d_in[14], (const float*)d_in[20]};
    const float* L1w = (const float*)d_in[21]; const float* L1b = (const float*)d_in[22];
    const float* L2w = (const float*)d_in[23]; const float* L2b = (const float*)d_in[24];
    const float* L3w = (const float*)d_in[25]; const float* L3b = (const float*)d_in[26];

    char* wsp = (char*)d_ws;
    size_t featB = (size_t)N * DH * sizeof(float);
    size_t hsB   = (size_t)N * DH * sizeof(unsigned short);
    float* F_A = (float*)wsp; wsp += featB;
    float* F_B = (float*)wsp; wsp += featB;
    unsigned short* HS0 = (unsigned short*)F_B;              // alias: dead before F_B written
    unsigned short* HS1 = (unsigned short*)wsp; wsp += hsB;
    unsigned short* HS2 = (unsigned short*)wsp; wsp += hsB;
    unsigned short* Wfrag = (unsigned short*)wsp; wsp += 3 * 65536;
    int2*  rowinfo = (int2*)wsp;  wsp += (size_t)N * sizeof(int2);
    float* dinv    = (float*)wsp; wsp += (size_t)N * sizeof(float);
    int*   starts  = (int*)wsp;   wsp = align16(wsp + (size_t)(G + 1) * sizeof(int));
    // zeroed region: gcur + sumAcc + maxAcc (single memset)
    int*      gcur   = (int*)wsp;      wsp += (size_t)MAXB * sizeof(int);
    float*    sumAcc = (float*)wsp;    wsp += (size_t)G * 128 * sizeof(float);
    unsigned* maxAcc = (unsigned*)wsp; wsp += (size_t)G * 128 * sizeof(unsigned);
    size_t zeroBytes = (size_t)MAXB * sizeof(int) + (size_t)G * 128 * 8;
    int*   bbuf    = (int*)align16(wsp); wsp = (char*)bbuf + (size_t)MAXB * BCAP * sizeof(int);

    const int NB = (N + 127) >> 7;
    const int nblkA = 512;
    const int chunk = (E + nblkA - 1) / nblkA;

    hipMemsetAsync(gcur, 0, zeroBytes, stream);
    k_bucketA<<<nblkA + 48, 256, 0, stream>>>(src, dst, gcur, bbuf, batch, starts,
                                              W[0], W[1], W[2], Wfrag,
                                              E, NB, chunk, N, G);
    k_bfinal <<<NB, 256, 0, stream>>>(gcur, bbuf, rowinfo, dinv, N);

    int gemmGrid = (N + 63) / 64;
    int gathGrid = (N + 15) / 16;

    k_gemm0<<<gemmGrid, 256, 0, stream>>>(x, Wfrag, dinv, HS0, N);
    k_gather_mm<<<gathGrid, 256, 0, stream>>>(HS0, rowinfo, bbuf, dinv,
                                              cb[0], bm[0], bv[0], bg[0], bt[0],
                                              nullptr, F_A, Wfrag + 32768, HS1, N);
    k_gather_mm<<<gathGrid, 256, 0, stream>>>(HS1, rowinfo, bbuf, dinv,
                                              cb[1], bm[1], bv[1], bg[1], bt[1],
                                              F_A, F_B, Wfrag + 65536, HS2, N);
    k_gather_pool<<<gathGrid, 256, 0, stream>>>(HS2, rowinfo, bbuf, dinv,
                                                cb[2], bm[2], bv[2], bg[2], bt[2],
                                                F_B, batch, sumAcc, maxAcc, N);

    k_head<<<G, 128, 0, stream>>>(sumAcc, maxAcc, starts,
                                  L1w, L1b, L2w, L2b, L3w, L3b, (float*)d_out);
}

// Round 13
// 453.590 us; speedup vs baseline: 1.1042x; 1.0288x over previous
//
#include <hip/hip_runtime.h>
#include <math.h>

#define DH 128
#define EPSB 1e-5f
#define MAXB 832     // max buckets (N <= 106496)
#define BCAP 2560    // bucket capacity (mean ~2046 at E/N=16, +11 sigma)
#define LDAP 136     // padded LDS row stride (ushorts)

typedef __attribute__((ext_vector_type(8))) short short8;
typedef __attribute__((ext_vector_type(4))) float f32x4;

static __device__ __forceinline__ unsigned short f2bf(float f) {
    unsigned u = __float_as_uint(f);
    u += 0x7fffu + ((u >> 16) & 1u);
    return (unsigned short)(u >> 16);
}
static __device__ __forceinline__ float bf2f(unsigned short h) {
    return __uint_as_float(((unsigned)h) << 16);
}
static __device__ __forceinline__ float blo(unsigned u) { return __uint_as_float(u << 16); }
static __device__ __forceinline__ float bhi(unsigned u) { return __uint_as_float(u & 0xFFFF0000u); }

// ---------------- pass A: edge bucketing + graph bounds + W fragmentize ----------------

__launch_bounds__(256)
__global__ void k_bucketA(const int* __restrict__ src, const int* __restrict__ dst,
                          int* __restrict__ gcur, int* __restrict__ bbuf,
                          const int* __restrict__ batch, int* __restrict__ starts,
                          const float* __restrict__ W0, const float* __restrict__ W1,
                          const float* __restrict__ W2, unsigned short* __restrict__ Wf0,
                          int E, int NB, int chunk, int N, int G)
{
    const int t = threadIdx.x;

    if (blockIdx.x >= 512) {            // ---- W fragmentize ----
        int fid = (blockIdx.x - 512) * 4 + (t >> 6);   // 0..191
        int lane = t & 63;
        int l = fid >> 6, f = fid & 63;
        const float* W = (l == 0) ? W0 : (l == 1) ? W1 : W2;
        unsigned short* Wf = Wf0 + (size_t)l * 32768;
        int nt = f & 3, s = (f >> 2) & 3, p = (f >> 4) & 1, nh = f >> 5;
        int n = nh * 64 + nt * 16 + (lane & 15);
        int kbase = s * 32 + (lane >> 4) * 8;
        unsigned short o[8];
#pragma unroll
        for (int j = 0; j < 8; ++j) {
            float w = W[(size_t)(kbase + j) * DH + n];
            unsigned short h = f2bf(w);
            o[j] = p ? f2bf(w - bf2f(h)) : h;
        }
        unsigned short* d = Wf + (size_t)f * 512 + lane * 8;
        *(ushort4*)d       = make_ushort4(o[0], o[1], o[2], o[3]);
        *(ushort4*)(d + 4) = make_ushort4(o[4], o[5], o[6], o[7]);
        return;
    }

    __shared__ int cnt[MAXB];
    __shared__ int base[MAXB];

    for (int i = blockIdx.x * 256 + t; i < N; i += 512 * 256) {
        int b = batch[i];
        if (i == 0) { starts[0] = 0; starts[G] = N; }
        else if (batch[i - 1] != b) starts[b] = i;
    }

    for (int i = t; i < NB; i += 256) cnt[i] = 0;
    __syncthreads();
    const int e0 = blockIdx.x * chunk;
    const int e1 = min(E, e0 + chunk);
    for (int e = e0 + t; e < e1; e += 256)
        atomicAdd(&cnt[dst[e] >> 7], 1);
    __syncthreads();
    for (int i = t; i < NB; i += 256) {
        int c = cnt[i];
        base[i] = (c > 0) ? atomicAdd(&gcur[i], c) : 0;
        cnt[i] = 0;
    }
    __syncthreads();
    for (int e = e0 + t; e < e1; e += 256) {
        int d = dst[e];
        int b = d >> 7;
        int o = base[b] + atomicAdd(&cnt[b], 1);
        if (o < BCAP) bbuf[(size_t)b * BCAP + o] = (src[e] << 7) | (d & 127);
    }
}

// ---------------- fused pass B (bfinal) || layer-0 GEMM: block-role split ----------------
// gemm0 no longer needs dinv (hs stores unscaled u = X@W; gather applies dinv at read).
// blocks 0..NB-1: per-bucket deg/dinv/rowinfo + in-place csr scatter.
// blocks NB.. : 64-row GEMM tile, split-at-staging frag-region LDS, pure-MFMA K-loop.

__launch_bounds__(256)
__global__ void k_bf_gemm0(const int* __restrict__ gcur, int* __restrict__ bbuf,
                           int2* __restrict__ rowinfo, float* __restrict__ dinv,
                           const float* __restrict__ X,
                           const unsigned short* __restrict__ Wf,
                           unsigned short* __restrict__ hs,
                           int N, int NB)
{
    __shared__ __align__(16) unsigned char smem[32768];
    const int t = threadIdx.x;

    if (blockIdx.x < NB) {
        // ---------------- bfinal ----------------
        int* ebuf = (int*)smem;                       // BCAP ints = 10240 B
        int* dcnt = (int*)(smem + 10240);             // 128 ints
        int* sp   = (int*)(smem + 10752);             // 128 ints
        const int b = blockIdx.x;
        const int c = min(gcur[b], BCAP);
        const int base = b * BCAP;
        int* p = bbuf + base;
        for (int i = t; i < c; i += 256) ebuf[i] = p[i];
        if (t < 128) dcnt[t] = 0;
        __syncthreads();
        for (int i = t; i < c; i += 256) atomicAdd(&dcnt[ebuf[i] & 127], 1);
        __syncthreads();
        if (t < 128) sp[t] = dcnt[t];
        __syncthreads();
        for (int off = 1; off < 128; off <<= 1) {
            int u = (t < 128 && t >= off) ? sp[t - off] : 0;
            __syncthreads();
            if (t < 128) sp[t] += u;
            __syncthreads();
        }
        if (t < 128) {
            sp[t] -= dcnt[t];
            int d = b * 128 + t;
            if (d < N) {
                rowinfo[d] = make_int2(base + sp[t], base + sp[t] + dcnt[t]);
                dinv[d] = rsqrtf((float)(dcnt[t] + 1));
            }
            dcnt[t] = 0;
        }
        __syncthreads();
        for (int i = t; i < c; i += 256) {
            int e = ebuf[i];
            int dl = e & 127;
            int o = atomicAdd(&dcnt[dl], 1);
            p[sp[dl] + o] = e >> 7;
        }
        return;
    }

    // ---------------- gemm0: u = X @ W (unscaled), bf16x3 split ----------------
    unsigned short* Ah = (unsigned short*)smem;             // 16 KB
    unsigned short* Al = (unsigned short*)(smem + 16384);   // 16 KB

    const int lane = t & 63, wave = t >> 6;
    const int mh = wave >> 1, nh = wave & 1;
    const int rowBase = (blockIdx.x - NB) * 64;
    const int r15 = lane & 15, quad = lane >> 4;

    {
        const int gl = t >> 4;
        const int f8 = (t & 15) * 8;
        const int s  = f8 >> 5;
        const int q  = (f8 >> 3) & 3;
        const int lp = q * 16 + gl;
#pragma unroll
        for (int it = 0; it < 4; ++it) {
            int row = rowBase + it * 16 + gl;
            float v[8];
            if (row < N) {
                float4 a0 = *(const float4*)(X + (size_t)row * DH + f8);
                float4 a1 = *(const float4*)(X + (size_t)row * DH + f8 + 4);
                v[0] = a0.x; v[1] = a0.y; v[2] = a0.z; v[3] = a0.w;
                v[4] = a1.x; v[5] = a1.y; v[6] = a1.z; v[7] = a1.w;
            } else {
#pragma unroll
                for (int j = 0; j < 8; ++j) v[j] = 0.f;
            }
            unsigned short hA[8], lA[8];
#pragma unroll
            for (int j = 0; j < 8; ++j) {
                unsigned short h = f2bf(v[j]);
                hA[j] = h; lA[j] = f2bf(v[j] - bf2f(h));
            }
            int reg = it * 4 + s;
            *(ushort4*)(Ah + reg * 512 + lp * 8)     = make_ushort4(hA[0], hA[1], hA[2], hA[3]);
            *(ushort4*)(Ah + reg * 512 + lp * 8 + 4) = make_ushort4(hA[4], hA[5], hA[6], hA[7]);
            *(ushort4*)(Al + reg * 512 + lp * 8)     = make_ushort4(lA[0], lA[1], lA[2], lA[3]);
            *(ushort4*)(Al + reg * 512 + lp * 8 + 4) = make_ushort4(lA[4], lA[5], lA[6], lA[7]);
        }
    }
    __syncthreads();

    f32x4 acc[2][4];
#pragma unroll
    for (int mt = 0; mt < 2; ++mt)
#pragma unroll
        for (int nt = 0; nt < 4; ++nt)
            acc[mt][nt] = (f32x4){0.f, 0.f, 0.f, 0.f};

#pragma unroll
    for (int s = 0; s < 4; ++s) {
        short8 wfh[4], wfl[4];
#pragma unroll
        for (int nt = 0; nt < 4; ++nt) {
            wfh[nt] = *(const short8*)(Wf + ((((nh * 2 + 0) * 4 + s) * 4 + nt) * 512) + lane * 8);
            wfl[nt] = *(const short8*)(Wf + ((((nh * 2 + 1) * 4 + s) * 4 + nt) * 512) + lane * 8);
        }
#pragma unroll
        for (int mt = 0; mt < 2; ++mt) {
            int reg = (mh * 2 + mt) * 4 + s;
            short8 ah = *(const short8*)(Ah + reg * 512 + lane * 8);
            short8 al = *(const short8*)(Al + reg * 512 + lane * 8);
#pragma unroll
            for (int nt = 0; nt < 4; ++nt) {
                acc[mt][nt] = __builtin_amdgcn_mfma_f32_16x16x32_bf16(ah, wfh[nt], acc[mt][nt], 0, 0, 0);
                acc[mt][nt] = __builtin_amdgcn_mfma_f32_16x16x32_bf16(ah, wfl[nt], acc[mt][nt], 0, 0, 0);
                acc[mt][nt] = __builtin_amdgcn_mfma_f32_16x16x32_bf16(al, wfh[nt], acc[mt][nt], 0, 0, 0);
            }
        }
    }

#pragma unroll
    for (int mt = 0; mt < 2; ++mt) {
        int rl = mh * 32 + mt * 16 + quad * 4;
#pragma unroll
        for (int reg = 0; reg < 4; ++reg) {
            int row = rowBase + rl + reg;
            if (row < N) {
#pragma unroll
                for (int nt = 0; nt < 4; ++nt)
                    hs[(size_t)row * DH + nh * 64 + nt * 16 + r15] = f2bf(acc[mt][nt][reg]);
            }
        }
    }
}

// ---------------- fused gather + post + next-layer MFMA GEMM ----------------
// hs holds unscaled u; gather computes a = dinv[d]*u[d] + sum dinv[s]*u[s]; out pre-BN = dinv[d]*a.

__launch_bounds__(256)
__global__ void k_gather_mm(const unsigned short* __restrict__ hs,
                            const int2* __restrict__ rowinfo,
                            const int* __restrict__ csr_src,
                            const float* __restrict__ dinv,
                            const float* __restrict__ cb, const float* __restrict__ bm,
                            const float* __restrict__ bv, const float* __restrict__ bg,
                            const float* __restrict__ bb,
                            const float* __restrict__ prev,
                            float* __restrict__ feat,
                            const unsigned short* __restrict__ Wf,
                            unsigned short* __restrict__ hs_next,
                            int N)
{
    __shared__ unsigned short Ah[16 * LDAP];
    __shared__ unsigned short Al[16 * LDAP];

    const int tid = threadIdx.x;
    const int nb = tid >> 4, lh = tid & 15;
    const int nodeBase = blockIdx.x * 16;
    const int node = nodeBase + nb;
    const int f = lh * 8;

    if (node < N) {
        int2 ri = rowinfo[node];
        const float dn = dinv[node];
        const uint4* hsv = (const uint4*)hs;
        float a[8];
        {
            uint4 sv = hsv[(size_t)node * 16 + lh];   // self-loop: dinv[d]*u[d]
            a[0] = dn * blo(sv.x); a[1] = dn * bhi(sv.x);
            a[2] = dn * blo(sv.y); a[3] = dn * bhi(sv.y);
            a[4] = dn * blo(sv.z); a[5] = dn * bhi(sv.z);
            a[6] = dn * blo(sv.w); a[7] = dn * bhi(sv.w);
        }
        for (int base = ri.x; base < ri.y; base += 16) {
            int cnt = ri.y - base; if (cnt > 16) cnt = 16;
            int idx = (lh < cnt) ? csr_src[base + lh] : 0;
            float dvl = dinv[idx];
            int i = 0;
            for (; i + 4 <= cnt; i += 4) {
                int s0 = __shfl(idx, i,     16), s1 = __shfl(idx, i + 1, 16);
                int s2 = __shfl(idx, i + 2, 16), s3 = __shfl(idx, i + 3, 16);
                float d0 = __shfl(dvl, i,     16), d1 = __shfl(dvl, i + 1, 16);
                float d2 = __shfl(dvl, i + 2, 16), d3 = __shfl(dvl, i + 3, 16);
                uint4 v0 = hsv[(size_t)s0 * 16 + lh];
                uint4 v1 = hsv[(size_t)s1 * 16 + lh];
                uint4 v2 = hsv[(size_t)s2 * 16 + lh];
                uint4 v3 = hsv[(size_t)s3 * 16 + lh];
                a[0] += (d0 * blo(v0.x) + d1 * blo(v1.x)) + (d2 * blo(v2.x) + d3 * blo(v3.x));
                a[1] += (d0 * bhi(v0.x) + d1 * bhi(v1.x)) + (d2 * bhi(v2.x) + d3 * bhi(v3.x));
                a[2] += (d0 * blo(v0.y) + d1 * blo(v1.y)) + (d2 * blo(v2.y) + d3 * blo(v3.y));
                a[3] += (d0 * bhi(v0.y) + d1 * bhi(v1.y)) + (d2 * bhi(v2.y) + d3 * bhi(v3.y));
                a[4] += (d0 * blo(v0.z) + d1 * blo(v1.z)) + (d2 * blo(v2.z) + d3 * blo(v3.z));
                a[5] += (d0 * bhi(v0.z) + d1 * bhi(v1.z)) + (d2 * bhi(v2.z) + d3 * bhi(v3.z));
                a[6] += (d0 * blo(v0.w) + d1 * blo(v1.w)) + (d2 * blo(v2.w) + d3 * blo(v3.w));
                a[7] += (d0 * bhi(v0.w) + d1 * bhi(v1.w)) + (d2 * bhi(v2.w) + d3 * bhi(v3.w));
            }
            for (; i < cnt; ++i) {
                int s = __shfl(idx, i, 16);
                float dd = __shfl(dvl, i, 16);
                uint4 v = hsv[(size_t)s * 16 + lh];
                a[0] += dd * blo(v.x); a[1] += dd * bhi(v.x);
                a[2] += dd * blo(v.y); a[3] += dd * bhi(v.y);
                a[4] += dd * blo(v.z); a[5] += dd * bhi(v.z);
                a[6] += dd * blo(v.w); a[7] += dd * bhi(v.w);
            }
        }

        float cbv[8], bmv[8], bvv[8], bgv[8], bbv[8];
        *(float4*)cbv = *(const float4*)(cb + f); *(float4*)(cbv + 4) = *(const float4*)(cb + f + 4);
        *(float4*)bmv = *(const float4*)(bm + f); *(float4*)(bmv + 4) = *(const float4*)(bm + f + 4);
        *(float4*)bvv = *(const float4*)(bv + f); *(float4*)(bvv + 4) = *(const float4*)(bv + f + 4);
        *(float4*)bgv = *(const float4*)(bg + f); *(float4*)(bgv + 4) = *(const float4*)(bg + f + 4);
        *(float4*)bbv = *(const float4*)(bb + f); *(float4*)(bbv + 4) = *(const float4*)(bb + f + 4);

        float o[8];
#pragma unroll
        for (int j = 0; j < 8; ++j) {
            float v = (a[j] * dn + cbv[j] - bmv[j]) * rsqrtf(bvv[j] + EPSB) * bgv[j] + bbv[j];
            o[j] = fmaxf(v, 0.f);
        }
        if (prev) {
            float4 p0 = *(const float4*)(prev + (size_t)node * DH + f);
            float4 p1 = *(const float4*)(prev + (size_t)node * DH + f + 4);
            o[0] += p0.x; o[1] += p0.y; o[2] += p0.z; o[3] += p0.w;
            o[4] += p1.x; o[5] += p1.y; o[6] += p1.z; o[7] += p1.w;
        }
        *(float4*)(feat + (size_t)node * DH + f)     = make_float4(o[0], o[1], o[2], o[3]);
        *(float4*)(feat + (size_t)node * DH + f + 4) = make_float4(o[4], o[5], o[6], o[7]);

        unsigned short hA[8], lA[8];
#pragma unroll
        for (int j = 0; j < 8; ++j) {
            unsigned short h = f2bf(o[j]);
            hA[j] = h; lA[j] = f2bf(o[j] - bf2f(h));
        }
        *(ushort4*)(Ah + nb * LDAP + f)     = make_ushort4(hA[0], hA[1], hA[2], hA[3]);
        *(ushort4*)(Ah + nb * LDAP + f + 4) = make_ushort4(hA[4], hA[5], hA[6], hA[7]);
        *(ushort4*)(Al + nb * LDAP + f)     = make_ushort4(lA[0], lA[1], lA[2], lA[3]);
        *(ushort4*)(Al + nb * LDAP + f + 4) = make_ushort4(lA[4], lA[5], lA[6], lA[7]);
    }
    __syncthreads();

    // ---- MFMA phase: u_next = feat @ W (unscaled) ----
    const int lane = tid & 63, wave = tid >> 6;
    const int r15 = lane & 15, quad = lane >> 4;

    f32x4 acc[2];
    acc[0] = (f32x4){0.f, 0.f, 0.f, 0.f};
    acc[1] = (f32x4){0.f, 0.f, 0.f, 0.f};

#pragma unroll
    for (int s = 0; s < 4; ++s) {
        short8 ah = *(const short8*)(Ah + r15 * LDAP + s * 32 + quad * 8);
        short8 al = *(const short8*)(Al + r15 * LDAP + s * 32 + quad * 8);
#pragma unroll
        for (int j = 0; j < 2; ++j) {
            int ntg = wave * 2 + j;
            int nh = ntg >> 2, nt = ntg & 3;
            short8 wh = *(const short8*)(Wf + ((((nh * 2 + 0) * 4 + s) * 4 + nt) * 512) + lane * 8);
            short8 wl = *(const short8*)(Wf + ((((nh * 2 + 1) * 4 + s) * 4 + nt) * 512) + lane * 8);
            acc[j] = __builtin_amdgcn_mfma_f32_16x16x32_bf16(ah, wh, acc[j], 0, 0, 0);
            acc[j] = __builtin_amdgcn_mfma_f32_16x16x32_bf16(ah, wl, acc[j], 0, 0, 0);
            acc[j] = __builtin_amdgcn_mfma_f32_16x16x32_bf16(al, wh, acc[j], 0, 0, 0);
        }
    }

#pragma unroll
    for (int j = 0; j < 2; ++j) {
        int col = (wave * 2 + j) * 16 + r15;
#pragma unroll
        for (int reg = 0; reg < 4; ++reg) {
            int row = nodeBase + quad * 4 + reg;
            if (row < N)
                hs_next[(size_t)row * DH + col] = f2bf(acc[j][reg]);
        }
    }
}

// ---------------- final gather + fused POOL (staged tree reduction, no LDS atomics) --------

__launch_bounds__(256)
__global__ void k_gather_pool(const unsigned short* __restrict__ hs,
                              const int2* __restrict__ rowinfo,
                              const int* __restrict__ csr_src,
                              const float* __restrict__ dinv,
                              const float* __restrict__ cb, const float* __restrict__ bm,
                              const float* __restrict__ bv, const float* __restrict__ bg,
                              const float* __restrict__ bb,
                              const float* __restrict__ prev,
                              const int* __restrict__ batch,
                              float* __restrict__ sumAcc,       // [G*128]
                              unsigned* __restrict__ maxAcc,    // [G*128]
                              int N)
{
    __shared__ float fsh[16][128];
    __shared__ float psum[2][2][128];
    __shared__ float pmax[2][2][128];
    __shared__ int   sb[16];

    const int tid = threadIdx.x;
    const int nb = tid >> 4, lh = tid & 15;
    const int nodeBase = blockIdx.x * 16;
    const int node = nodeBase + nb;
    const int f = lh * 8;

    const int g0 = batch[nodeBase];
    const int g1 = batch[min(nodeBase + 15, N - 1)];

    if (tid < 16) {
        int nn = nodeBase + tid;
        sb[tid] = (nn < N && batch[nn] != g0) ? 1 : 0;
    }
    if (nodeBase + 16 > N) {
        if (node >= N) {
#pragma unroll
            for (int j = 0; j < 8; ++j) fsh[nb][f + j] = 0.f;
        }
    }

    if (node < N) {
        int2 ri = rowinfo[node];
        const float dn = dinv[node];
        const uint4* hsv = (const uint4*)hs;
        float a[8];
        {
            uint4 sv = hsv[(size_t)node * 16 + lh];
            a[0] = dn * blo(sv.x); a[1] = dn * bhi(sv.x);
            a[2] = dn * blo(sv.y); a[3] = dn * bhi(sv.y);
            a[4] = dn * blo(sv.z); a[5] = dn * bhi(sv.z);
            a[6] = dn * blo(sv.w); a[7] = dn * bhi(sv.w);
        }
        for (int base = ri.x; base < ri.y; base += 16) {
            int cnt = ri.y - base; if (cnt > 16) cnt = 16;
            int idx = (lh < cnt) ? csr_src[base + lh] : 0;
            float dvl = dinv[idx];
            int i = 0;
            for (; i + 4 <= cnt; i += 4) {
                int s0 = __shfl(idx, i,     16), s1 = __shfl(idx, i + 1, 16);
                int s2 = __shfl(idx, i + 2, 16), s3 = __shfl(idx, i + 3, 16);
                float d0 = __shfl(dvl, i,     16), d1 = __shfl(dvl, i + 1, 16);
                float d2 = __shfl(dvl, i + 2, 16), d3 = __shfl(dvl, i + 3, 16);
                uint4 v0 = hsv[(size_t)s0 * 16 + lh];
                uint4 v1 = hsv[(size_t)s1 * 16 + lh];
                uint4 v2 = hsv[(size_t)s2 * 16 + lh];
                uint4 v3 = hsv[(size_t)s3 * 16 + lh];
                a[0] += (d0 * blo(v0.x) + d1 * blo(v1.x)) + (d2 * blo(v2.x) + d3 * blo(v3.x));
                a[1] += (d0 * bhi(v0.x) + d1 * bhi(v1.x)) + (d2 * bhi(v2.x) + d3 * bhi(v3.x));
                a[2] += (d0 * blo(v0.y) + d1 * blo(v1.y)) + (d2 * blo(v2.y) + d3 * blo(v3.y));
                a[3] += (d0 * bhi(v0.y) + d1 * bhi(v1.y)) + (d2 * bhi(v2.y) + d3 * bhi(v3.y));
                a[4] += (d0 * blo(v0.z) + d1 * blo(v1.z)) + (d2 * blo(v2.z) + d3 * blo(v3.z));
                a[5] += (d0 * bhi(v0.z) + d1 * bhi(v1.z)) + (d2 * bhi(v2.z) + d3 * bhi(v3.z));
                a[6] += (d0 * blo(v0.w) + d1 * blo(v1.w)) + (d2 * blo(v2.w) + d3 * blo(v3.w));
                a[7] += (d0 * bhi(v0.w) + d1 * bhi(v1.w)) + (d2 * bhi(v2.w) + d3 * bhi(v3.w));
            }
            for (; i < cnt; ++i) {
                int s = __shfl(idx, i, 16);
                float dd = __shfl(dvl, i, 16);
                uint4 v = hsv[(size_t)s * 16 + lh];
                a[0] += dd * blo(v.x); a[1] += dd * bhi(v.x);
                a[2] += dd * blo(v.y); a[3] += dd * bhi(v.y);
                a[4] += dd * blo(v.z); a[5] += dd * bhi(v.z);
                a[6] += dd * blo(v.w); a[7] += dd * bhi(v.w);
            }
        }

        float cbv[8], bmv[8], bvv[8], bgv[8], bbv[8];
        *(float4*)cbv = *(const float4*)(cb + f); *(float4*)(cbv + 4) = *(const float4*)(cb + f + 4);
        *(float4*)bmv = *(const float4*)(bm + f); *(float4*)(bmv + 4) = *(const float4*)(bm + f + 4);
        *(float4*)bvv = *(const float4*)(bv + f); *(float4*)(bvv + 4) = *(const float4*)(bv + f + 4);
        *(float4*)bgv = *(const float4*)(bg + f); *(float4*)(bgv + 4) = *(const float4*)(bg + f + 4);
        *(float4*)bbv = *(const float4*)(bb + f); *(float4*)(bbv + 4) = *(const float4*)(bb + f + 4);

        float4 p0 = *(const float4*)(prev + (size_t)node * DH + f);
        float4 p1 = *(const float4*)(prev + (size_t)node * DH + f + 4);
        float o[8];
#pragma unroll
        for (int j = 0; j < 8; ++j) {
            float v = (a[j] * dn + cbv[j] - bmv[j]) * rsqrtf(bvv[j] + EPSB) * bgv[j] + bbv[j];
            o[j] = fmaxf(v, 0.f);
        }
        o[0] += p0.x; o[1] += p0.y; o[2] += p0.z; o[3] += p0.w;
        o[4] += p1.x; o[5] += p1.y; o[6] += p1.z; o[7] += p1.w;

        *(float4*)(&fsh[nb][f])     = make_float4(o[0], o[1], o[2], o[3]);
        *(float4*)(&fsh[nb][f + 4]) = make_float4(o[4], o[5], o[6], o[7]);
    }
    __syncthreads();

    const int half = tid >> 7;
    const int fi = tid & 127;
    float s0 = 0.f, s1 = 0.f, m0 = 0.f, m1 = 0.f;
#pragma unroll
    for (int r = 0; r < 8; ++r) {
        int row = half * 8 + r;
        float v = fsh[row][fi];
        if (sb[row]) { s1 += v; m1 = fmaxf(m1, v); }
        else         { s0 += v; m0 = fmaxf(m0, v); }
    }
    psum[half][0][fi] = s0; psum[half][1][fi] = s1;
    pmax[half][0][fi] = m0; pmax[half][1][fi] = m1;
    __syncthreads();

    if (half == 0) {
        float ts0 = psum[0][0][fi] + psum[1][0][fi];
        float tm0 = fmaxf(pmax[0][0][fi], pmax[1][0][fi]);
        unsafeAtomicAdd(&sumAcc[(size_t)g0 * 128 + fi], ts0);
        atomicMax(&maxAcc[(size_t)g0 * 128 + fi], __float_as_uint(tm0));
        if (g1 != g0) {
            float ts1 = psum[0][1][fi] + psum[1][1][fi];
            float tm1 = fmaxf(pmax[0][1][fi], pmax[1][1][fi]);
            unsafeAtomicAdd(&sumAcc[(size_t)g1 * 128 + fi], ts1);
            atomicMax(&maxAcc[(size_t)g1 * 128 + fi], __float_as_uint(tm1));
        }
    }
}

// ---------------- MLP head ----------------

__launch_bounds__(128)
__global__ void k_head(const float* __restrict__ sumAcc, const unsigned* __restrict__ maxAcc,
                       const int* __restrict__ starts,
                       const float* __restrict__ L1w, const float* __restrict__ L1b,
                       const float* __restrict__ L2w, const float* __restrict__ L2b,
                       const float* __restrict__ L3w, const float* __restrict__ L3b,
                       float* __restrict__ out)
{
    int g = blockIdx.x, t = threadIdx.x;
    float cnt = (float)(starts[g + 1] - starts[g]);

    __shared__ float h[256];
    h[t]       = sumAcc[(size_t)g * 128 + t] / cnt;
    h[128 + t] = __uint_as_float(maxAcc[(size_t)g * 128 + t]);
    __syncthreads();

    float a = L1b[t];
    for (int k = 0; k < 256; ++k) a += h[k] * L1w[k * DH + t];
    __shared__ float h1[128];
    h1[t] = fmaxf(a, 0.f);
    __syncthreads();

    __shared__ float h2[64];
    if (t < 64) {
        float a2 = L2b[t];
        for (int k = 0; k < 128; ++k) a2 += h1[k] * L2w[k * 64 + t];
        h2[t] = fmaxf(a2, 0.f);
    }
    __syncthreads();

    if (t < 64) {
        float p = h2[t] * L3w[t];
#pragma unroll
        for (int off = 32; off > 0; off >>= 1) p += __shfl_down(p, off, 64);
        if (t == 0) out[g] = p + L3b[0];
    }
}

// ---------------- launch ----------------

static inline char* align16(char* p) {
    return (char*)(((uintptr_t)p + 15) & ~(uintptr_t)15);
}

extern "C" void kernel_launch(void* const* d_in, const int* in_sizes, int n_in,
                              void* d_out, int out_size, void* d_ws, size_t ws_size,
                              hipStream_t stream)
{
    const float* x     = (const float*)d_in[0];
    const int*   ei    = (const int*)d_in[1];
    const int*   batch = (const int*)d_in[2];
    const int N = in_sizes[0] / DH;
    const int E = in_sizes[1] / 2;
    const int G = out_size;
    const int* src = ei;
    const int* dst = ei + E;

    const float* W[3]  = {(const float*)d_in[3],  (const float*)d_in[9],  (const float*)d_in[15]};
    const float* cb[3] = {(const float*)d_in[4],  (const float*)d_in[10], (const float*)d_in[16]};
    const float* bg[3] = {(const float*)d_in[5],  (const float*)d_in[11], (const float*)d_in[17]};
    const float* bt[3] = {(const float*)d_in[6],  (const float*)d_in[12], (const float*)d_in[18]};
    const float* bm[3] = {(const float*)d_in[7],  (const float*)d_in[13], (const float*)d_in[19]};
    const float* bv[3] = {(const float*)d_in[8],  (const float*)d_in[14], (const float*)d_in[20]};
    const float* L1w = (const float*)d_in[21]; const float* L1b = (const float*)d_in[22];
    const float* L2w = (const float*)d_in[23]; const float* L2b = (const float*)d_in[24];
    const float* L3w = (const float*)d_in[25]; const float* L3b = (const float*)d_in[26];

    char* wsp = (char*)d_ws;
    size_t featB = (size_t)N * DH * sizeof(float);
    size_t hsB   = (size_t)N * DH * sizeof(unsigned short);
    float* F_A = (float*)wsp; wsp += featB;
    float* F_B = (float*)wsp; wsp += featB;
    unsigned short* HS0 = (unsigned short*)F_B;              // alias: dead before F_B written
    unsigned short* HS1 = (unsigned short*)wsp; wsp += hsB;
    unsigned short* HS2 = (unsigned short*)wsp; wsp += hsB;
    unsigned short* Wfrag = (unsigned short*)wsp; wsp += 3 * 65536;
    int2*  rowinfo = (int2*)wsp;  wsp += (size_t)N * sizeof(int2);
    float* dinv    = (float*)wsp; wsp += (size_t)N * sizeof(float);
    int*   starts  = (int*)wsp;   wsp = align16(wsp + (size_t)(G + 1) * sizeof(int));
    // zeroed region: gcur + sumAcc + maxAcc (single memset)
    int*      gcur   = (int*)wsp;      wsp += (size_t)MAXB * sizeof(int);
    float*    sumAcc = (float*)wsp;    wsp += (size_t)G * 128 * sizeof(float);
    unsigned* maxAcc = (unsigned*)wsp; wsp += (size_t)G * 128 * sizeof(unsigned);
    size_t zeroBytes = (size_t)MAXB * sizeof(int) + (size_t)G * 128 * 8;
    int*   bbuf    = (int*)align16(wsp); wsp = (char*)bbuf + (size_t)MAXB * BCAP * sizeof(int);

    const int NB = (N + 127) >> 7;
    const int nblkA = 512;
    const int chunk = (E + nblkA - 1) / nblkA;
    const int gemmGrid = (N + 63) / 64;
    const int gathGrid = (N + 15) / 16;

    hipMemsetAsync(gcur, 0, zeroBytes, stream);
    k_bucketA<<<nblkA + 48, 256, 0, stream>>>(src, dst, gcur, bbuf, batch, starts,
                                              W[0], W[1], W[2], Wfrag,
                                              E, NB, chunk, N, G);
    // fused: bfinal (blocks 0..NB-1) || gemm0 (blocks NB..NB+gemmGrid-1)
    k_bf_gemm0<<<NB + gemmGrid, 256, 0, stream>>>(gcur, bbuf, rowinfo, dinv,
                                                  x, Wfrag, HS0, N, NB);
    k_gather_mm<<<gathGrid, 256, 0, stream>>>(HS0, rowinfo, bbuf, dinv,
                                              cb[0], bm[0], bv[0], bg[0], bt[0],
                                              nullptr, F_A, Wfrag + 32768, HS1, N);
    k_gather_mm<<<gathGrid, 256, 0, stream>>>(HS1, rowinfo, bbuf, dinv,
                                              cb[1], bm[1], bv[1], bg[1], bt[1],
                                              F_A, F_B, Wfrag + 65536, HS2, N);
    k_gather_pool<<<gathGrid, 256, 0, stream>>>(HS2, rowinfo, bbuf, dinv,
                                                cb[2], bm[2], bv[2], bg[2], bt[2],
                                                F_B, batch, sumAcc, maxAcc, N);

    k_head<<<G, 128, 0, stream>>>(sumAcc, maxAcc, starts,
                                  L1w, L1b, L2w, L2b, L3w, L3b, (float*)d_out);
}